// Round 10
// baseline (3448.326 us; speedup 1.0000x reference)
//
#include <hip/hip_runtime.h>
#include <hip/hip_fp16.h>
#include <stdint.h>

#define Bsz 64
#define Tsz 1024
#define Dsz 256
#define UNITSn 256
#define Zdim 1024      // 4*UNITS

typedef _Float16 f16x8  __attribute__((ext_vector_type(8)));
typedef float    f32x4  __attribute__((ext_vector_type(4)));

#define MFMA16(D, A, B) D = __builtin_amdgcn_mfma_f32_16x16x32_f16( \
    __builtin_bit_cast(f16x8, A), __builtin_bit_cast(f16x8, B), D, 0, 0, 0)

__device__ __forceinline__ float sigm(float x)   { return 1.0f / (1.0f + __expf(-x)); }
__device__ __forceinline__ float tanh_f(float x) { return 1.0f - 2.0f / (__expf(2.0f * x) + 1.0f); }

// U[256][1024] fp32 -> UT[1024][256] f16 (transposed, k-contiguous)
__global__ __launch_bounds__(256) void convert_u(const float* __restrict__ U,
                                                 _Float16* __restrict__ UT) {
  int i = blockIdx.x * 256 + threadIdx.x;   // 262144
  int n = i >> 8, k = i & 255;
  UT[i] = (_Float16)U[(size_t)k * Zdim + n];
}

// W[256][1024] fp32 -> MFMA B-fragments for lstm v10.
// Fragment f = ks*8 + nt (ks=0..7 k-slices of 32; nt=0..7 = g*2+sub), per
// thread t = w*64+l: lane l holds W[k = ks*32+(l>>4)*8+j][col = g*256+w*32+
// sub*16+(l&15)], j=0..7 packed as 4 f16-pair dwords (same B layout as
// proj_mfma's verified uf fragments).
//  f 0..43  -> Wres (reg/AGPR resident)
//  f 44..51 -> Wldsb (LDS)
//  f 52..63 -> Wstrb (L2 stream)
__global__ __launch_bounds__(256) void convert_w10(const float* __restrict__ W,
                                                   uint4* __restrict__ Wres,
                                                   uint4* __restrict__ Wldsb,
                                                   uint4* __restrict__ Wstrb) {
  int i = blockIdx.x * 256 + threadIdx.x;   // 64*512 = 32768 uint4
  if (i >= 32768) return;
  int f = i >> 9, t = i & 511;
  int w = t >> 6, l = t & 63;
  int ks = f >> 3, nt = f & 7;
  int g = nt >> 1, sub = nt & 1;
  int col = g * 256 + w * 32 + sub * 16 + (l & 15);
  int kb = ks * 32 + ((l >> 4) << 3);
  uint32_t d[4];
#pragma unroll
  for (int e = 0; e < 4; e++) {
    int k = kb + 2 * e;
    float w0 = W[(size_t)k * Zdim + col];
    float w1 = W[(size_t)(k + 1) * Zdim + col];
    __half2 p = __floats2half2_rn(w0, w1);
    d[e] = __builtin_bit_cast(uint32_t, p);
  }
  uint4 v = make_uint4(d[0], d[1], d[2], d[3]);
  if (f < 44)      Wres[f * 512 + t] = v;
  else if (f < 52) Wldsb[(f - 44) * 512 + t] = v;
  else             Wstrb[(f - 52) * 512 + t] = v;
}

// xz[(tloc*64+b)*1024+n] = x[b][t][:] @ U[:,n] + bias[n] via f16 MFMA. (verified)
__global__ __launch_bounds__(256) void proj_mfma(
    const float* __restrict__ x, const _Float16* __restrict__ UT,
    const float* __restrict__ bias, float* __restrict__ xz, int t0) {
  __shared__ _Float16 Ax[64][40];
  __shared__ _Float16 Ux[256][40];
  const int tid  = threadIdx.x;
  const int w    = tid >> 6, lane = tid & 63;
  const int lr   = lane & 15, kg = lane >> 4;
  const int n0   = blockIdx.x * 256;
  const int tloc = blockIdx.y;
  const int t    = t0 + tloc;
  const int arow = tid >> 2, ak = (tid & 3) * 8;

  f32x4 acc[4][4];
#pragma unroll
  for (int mi = 0; mi < 4; mi++)
#pragma unroll
    for (int ni = 0; ni < 4; ni++) acc[mi][ni] = f32x4{0.f, 0.f, 0.f, 0.f};

  for (int k0 = 0; k0 < Dsz; k0 += 32) {
    const float* xp = x + ((size_t)arow * Tsz + t) * Dsz + k0 + ak;
    float4 p0 = *(const float4*)xp;
    float4 p1 = *(const float4*)(xp + 4);
    const _Float16* up = UT + (size_t)(n0 + tid) * Dsz + k0;
    f16x8 u0 = *(const f16x8*)up;
    f16x8 u1 = *(const f16x8*)(up + 8);
    f16x8 u2 = *(const f16x8*)(up + 16);
    f16x8 u3 = *(const f16x8*)(up + 24);
    __syncthreads();
    f16x8 a8;
    a8[0] = (_Float16)p0.x; a8[1] = (_Float16)p0.y;
    a8[2] = (_Float16)p0.z; a8[3] = (_Float16)p0.w;
    a8[4] = (_Float16)p1.x; a8[5] = (_Float16)p1.y;
    a8[6] = (_Float16)p1.z; a8[7] = (_Float16)p1.w;
    *(f16x8*)&Ax[arow][ak] = a8;
    *(f16x8*)&Ux[tid][0]  = u0;
    *(f16x8*)&Ux[tid][8]  = u1;
    *(f16x8*)&Ux[tid][16] = u2;
    *(f16x8*)&Ux[tid][24] = u3;
    __syncthreads();
    f16x8 af[4], uf[4];
#pragma unroll
    for (int mi = 0; mi < 4; mi++) af[mi] = *(const f16x8*)&Ax[mi * 16 + lr][kg * 8];
#pragma unroll
    for (int ni = 0; ni < 4; ni++) uf[ni] = *(const f16x8*)&Ux[w * 64 + ni * 16 + lr][kg * 8];
#pragma unroll
    for (int mi = 0; mi < 4; mi++)
#pragma unroll
      for (int ni = 0; ni < 4; ni++)
        acc[mi][ni] = __builtin_amdgcn_mfma_f32_16x16x32_f16(af[mi], uf[ni],
                                                             acc[mi][ni], 0, 0, 0);
  }
#pragma unroll
  for (int ni = 0; ni < 4; ni++) {
    int col = n0 + w * 64 + ni * 16 + lr;
    float bs = bias[col];
#pragma unroll
    for (int mi = 0; mi < 4; mi++) {
      f32x4 v = acc[mi][ni];
#pragma unroll
      for (int r = 0; r < 4; r++) {
        int brow = mi * 16 + kg * 4 + r;
        xz[((size_t)tloc * 64 + brow) * Zdim + col] = v[r] + bs;
      }
    }
  }
}

// One WG (512 thr = 8 waves) per batch. MFMA recurrence: wave w owns units
// w*32..w*32+31 (all 4 gates; n-tiles g*16+2w{,+1}); per step 64 MFMA/wave.
// A = h broadcast (all 16 rows equal -> D rows all equal z). W fragments:
// 44 resident (reg/AGPR, MFMA reads AGPR natively), 8 LDS, 12 L2-stream.
// Static LDS 81 KB forces 1 WG/CU (2 waves/SIMD, 256-reg unified budget).
__global__ __launch_bounds__(512) void lstm_chunk(
    const float* __restrict__ xz, const uint4* __restrict__ Wres,
    const uint4* __restrict__ Wldsb, const uint4* __restrict__ Wstrb,
    float* __restrict__ out, uint4* __restrict__ h_state,
    float* __restrict__ c_state, int t0, int Tc, int n_out) {
  __shared__ uint4 Wl[8 * 512];     // 64 KB  (frags 44..51)
  __shared__ uint4 hq[2][32];       // 1 KB packed-f16 h, double-buffered
  __shared__ uint4 fence[1024];     // 16 KB occupancy fence

  const int tid = threadIdx.x;
  const int b   = blockIdx.x;
  const int w   = tid >> 6, l = tid & 63;
  const int kg  = l >> 4, l31 = l & 31;
  const int sub = kg & 1;

  if (h_state == nullptr) fence[tid & 1023] = make_uint4(0, 0, 0, 0);

  // resident W fragments (f 0..43) — compiler places across VGPR/AGPR
  uint4 wr[44];
#pragma unroll
  for (int s = 0; s < 44; s++) wr[s] = Wres[(size_t)s * 512 + tid];
  // LDS W fragments
#pragma unroll
  for (int s = 0; s < 8; s++) Wl[s * 512 + tid] = Wldsb[(size_t)s * 512 + tid];

  float c = 0.0f;
  if (t0 == 0) {
    if (tid < 64) ((uint4*)hq)[tid] = make_uint4(0, 0, 0, 0);
  } else {
    if (tid < 32) ((uint4*)hq)[tid] = h_state[(size_t)b * 32 + tid];
    c = c_state[(size_t)b * 256 + w * 32 + l31];
  }
  __syncthreads();

  const float* xzb = xz + (size_t)b * Zdim + w * 32 + l31;
  float nx0 = xzb[0], nx1 = xzb[256], nx2 = xzb[512], nx3 = xzb[768];
  const uint4* wsp = Wstrb + tid;

  for (int tl = 0; tl < Tc; tl++) {
    const int buf = tl & 1;
    const uint4* hb4 = hq[buf];     // 32 uint4 of packed-f16 h
    // stream pass-A ks7 frags (idx 4..7)
    uint4 sA0 = wsp[4 * 512], sA1 = wsp[5 * 512], sA2 = wsp[6 * 512], sA3 = wsp[7 * 512];

    // ---- pass A: n-tiles 0..3 (gates 0,1) ----
    f32x4 D0 = {0.f,0.f,0.f,0.f}, D1 = D0, D2 = D0, D3 = D0;
#pragma unroll
    for (int ks = 0; ks < 6; ks++) {          // resident f = ks*8 + nt
      uint4 A = hb4[ks * 4 + kg];
      MFMA16(D0, A, wr[ks * 8 + 0]); MFMA16(D1, A, wr[ks * 8 + 1]);
      MFMA16(D2, A, wr[ks * 8 + 2]); MFMA16(D3, A, wr[ks * 8 + 3]);
    }
    // stream pass-B frags (idx 0..3 = ks6 nt4..7, idx 8..11 = ks7 nt4..7)
    uint4 sB0 = wsp[0 * 512], sB1 = wsp[1 * 512], sB2 = wsp[2 * 512], sB3 = wsp[3 * 512];
    uint4 sC0 = wsp[8 * 512], sC1 = wsp[9 * 512], sC2 = wsp[10 * 512], sC3 = wsp[11 * 512];
    {   // ks6 -> LDS Wl[4+nt]
      uint4 A = hb4[6 * 4 + kg];
      uint4 b0 = Wl[4 * 512 + tid], b1 = Wl[5 * 512 + tid];
      uint4 b2 = Wl[6 * 512 + tid], b3 = Wl[7 * 512 + tid];
      MFMA16(D0, A, b0); MFMA16(D1, A, b1); MFMA16(D2, A, b2); MFMA16(D3, A, b3);
    }
    {   // ks7 -> stream sA
      uint4 A = hb4[7 * 4 + kg];
      MFMA16(D0, A, sA0); MFMA16(D1, A, sA1); MFMA16(D2, A, sA2); MFMA16(D3, A, sA3);
    }
    float z0 = sub ? D1[0] : D0[0];   // gate 0 (i)
    float z1 = sub ? D3[0] : D2[0];   // gate 1 (f)

    // ---- pass B: n-tiles 4..7 (gates 2,3) ----
    f32x4 E0 = {0.f,0.f,0.f,0.f}, E1 = E0, E2 = E0, E3 = E0;
#pragma unroll
    for (int ks = 0; ks < 5; ks++) {          // resident f = ks*8 + 4 + nt
      uint4 A = hb4[ks * 4 + kg];
      MFMA16(E0, A, wr[ks * 8 + 4]); MFMA16(E1, A, wr[ks * 8 + 5]);
      MFMA16(E2, A, wr[ks * 8 + 6]); MFMA16(E3, A, wr[ks * 8 + 7]);
    }
    {   // ks5 -> LDS Wl[0..3]
      uint4 A = hb4[5 * 4 + kg];
      uint4 b0 = Wl[0 * 512 + tid], b1 = Wl[1 * 512 + tid];
      uint4 b2 = Wl[2 * 512 + tid], b3 = Wl[3 * 512 + tid];
      MFMA16(E0, A, b0); MFMA16(E1, A, b1); MFMA16(E2, A, b2); MFMA16(E3, A, b3);
    }
    {   // ks6 -> stream sB
      uint4 A = hb4[6 * 4 + kg];
      MFMA16(E0, A, sB0); MFMA16(E1, A, sB1); MFMA16(E2, A, sB2); MFMA16(E3, A, sB3);
    }
    {   // ks7 -> stream sC
      uint4 A = hb4[7 * 4 + kg];
      MFMA16(E0, A, sC0); MFMA16(E1, A, sC1); MFMA16(E2, A, sC2); MFMA16(E3, A, sC3);
    }
    float z2 = sub ? E1[0] : E0[0];   // gate 2 (g)
    float z3 = sub ? E3[0] : E2[0];   // gate 3 (o)

    // ---- gates (all lanes; lanes 32..63 duplicate lanes 0..31) ----
    z0 += nx0; z1 += nx1; z2 += nx2; z3 += nx3;
    if (tl + 1 < Tc) {
      const float* xn = xzb + (size_t)(tl + 1) * (Bsz * Zdim);
      nx0 = xn[0]; nx1 = xn[256]; nx2 = xn[512]; nx3 = xn[768];
    }
    float ig = sigm(z0), fg = sigm(z1), gg = tanh_f(z2), og = sigm(z3);
    c = fg * c + ig * gg;
    float hn = og * tanh_f(c);
    if (l < 32) {
      int ot = (t0 + tl) - (Tsz - n_out);
      if (ot >= 0) out[((size_t)b * n_out + ot) * UNITSn + w * 32 + l] = hn;
      ((_Float16*)hq[buf ^ 1])[w * 32 + l] = (_Float16)hn;
    }
    __syncthreads();
  }
  if (tid < 32) h_state[(size_t)b * 32 + tid] = ((uint4*)hq)[(Tc & 1) * 32 + tid];
  if (l < 32) c_state[(size_t)b * 256 + w * 32 + l] = c;
}

extern "C" void kernel_launch(void* const* d_in, const int* in_sizes, int n_in,
                              void* d_out, int out_size, void* d_ws, size_t ws_size,
                              hipStream_t stream) {
  const float* x    = (const float*)d_in[0];
  const float* U    = (const float*)d_in[1];
  const float* W    = (const float*)d_in[2];
  const float* bias = (const float*)d_in[3];
  float* out = (float*)d_out;
  const int n_out = out_size / (Bsz * UNITSn);   // 32

  uint8_t* ws = (uint8_t*)d_ws;
  uint4* Wres     = (uint4*)ws;                    // 352 KB (f 0..43)
  uint4* Wldsb    = (uint4*)(ws + (352u << 10));   //  64 KB (f 44..51)
  uint4* Wstrb    = (uint4*)(ws + (416u << 10));   //  96 KB (f 52..63)
  _Float16* UT    = (_Float16*)(ws + (512u << 10));// 512 KB
  uint4* h_state  = (uint4*)(ws + (1024u << 10));  //  32 KB
  float* c_state  = (float*)(ws + (1056u << 10));  //  64 KB
  float* xz       = (float*)(ws + (2u << 20));     // Tc*64*1024 fp32

  int Tc = Tsz;
  while (Tc > 1 && (size_t)(2u << 20) + (size_t)Tc * (Bsz * Zdim) * 4 > ws_size) Tc >>= 1;

  convert_w10<<<dim3(128), dim3(256), 0, stream>>>(W, Wres, Wldsb, Wstrb);
  convert_u<<<dim3(1024), dim3(256), 0, stream>>>(U, UT);

  for (int t0 = 0; t0 < Tsz; t0 += Tc) {
    proj_mfma<<<dim3(4, Tc), dim3(256), 0, stream>>>(x, UT, bias, xz, t0);
    lstm_chunk<<<dim3(Bsz), dim3(512), 0, stream>>>(xz, Wres, Wldsb, Wstrb,
                                                    out, h_state, c_state,
                                                    t0, Tc, n_out);
  }
}